// Round 7
// baseline (160.503 us; speedup 1.0000x reference)
//
#include <hip/hip_runtime.h>
#include <math.h>

#define Bn   4
#define CIN  128
#define Hh   64
#define Ww   64
#define HW   4096
#define CMID 64
#define KOC  100      // (scale*k_up)^2
#define H2   128
#define W2d  128
#define HW2  16384
#define KUP  5
#define BN_EPS 1e-5f
#define CCH  8        // channels per carafe thread (16 chunks of 8)

// Padded W1 plane: 66 rows (1-row zero halo top+bottom) x 64 cols
#define PROWS 66
#define PPLANE (PROWS * Ww)          // 4224 floats per (b,cm)

// ---------------- Kernel A: 1x1 conv + BN(eval) + SiLU -> W1p [B][CMID][66][64]
// thread = 4 consecutive pixels (float4) x 2 co. First 32768 threads also zero
// the halo rows (rows 0 and 65 of each plane).
__global__ __launch_bounds__(256) void comp_kernel(
    const float* __restrict__ X,
    const float* __restrict__ cw,
    const float* __restrict__ cg,
    const float* __restrict__ cb,
    float* __restrict__ W1p)
{
    int gt  = blockIdx.x * blockDim.x + threadIdx.x;   // 512*256 = 131072 threads
    int pg  = gt & 1023;                               // pixel group (4 px)
    int cog = (gt >> 10) & 31;                         // 32 groups of 2 co
    int b   = gt >> 15;
    int pix = pg * 4;
    int co0 = cog * 2;

    // zero halo rows: 4b x 64cm x 2rows x 64w = 32768 elements
    if (gt < Bn * CMID * 2 * Ww) {
        int wz  = gt & 63;
        int r01 = (gt >> 6) & 1;
        int cmz = (gt >> 7) & 63;
        int bz  = gt >> 13;
        W1p[((size_t)(bz * CMID + cmz) * PROWS + (r01 ? (PROWS - 1) : 0)) * Ww + wz] = 0.f;
    }

    const float* xb = X + (size_t)b * CIN * HW + pix;
    float4 acc0 = make_float4(0.f, 0.f, 0.f, 0.f);
    float4 acc1 = make_float4(0.f, 0.f, 0.f, 0.f);

#pragma unroll 4
    for (int ci = 0; ci < CIN; ++ci) {
        float4 xv = *(const float4*)(xb + (size_t)ci * HW);
        float w0 = cw[(size_t)co0 * CIN + ci];
        float w1 = cw[(size_t)(co0 + 1) * CIN + ci];
        acc0.x += xv.x * w0; acc0.y += xv.y * w0; acc0.z += xv.z * w0; acc0.w += xv.w * w0;
        acc1.x += xv.x * w1; acc1.y += xv.y * w1; acc1.z += xv.z * w1; acc1.w += xv.w * w1;
    }

    float inv_s = rsqrtf(1.0f + BN_EPS);
    int h = pix >> 6, w = pix & 63;
#pragma unroll
    for (int g = 0; g < 2; ++g) {
        int co = co0 + g;
        float s  = cg[co] * inv_s;
        float bb = cb[co];
        float4 a = g ? acc1 : acc0;
        float4 r;
        float v;
        v = a.x * s + bb; r.x = v / (1.f + expf(-v));
        v = a.y * s + bb; r.y = v / (1.f + expf(-v));
        v = a.z * s + bb; r.z = v / (1.f + expf(-v));
        v = a.w * s + bb; r.w = v / (1.f + expf(-v));
        *(float4*)(W1p + ((size_t)(b * CMID + co) * PROWS + h + 1) * Ww + w) = r;
    }
}

// ---------------- Kernel B: 3x3 conv partial sums (cm split in half)
// thread = 4 consecutive w x 1 h x 2 ko over 32 input channels.
// Block weights (2 ko x 32 cm x 9 = 576 floats) staged in LDS once.
// half 0 -> W2a, half 1 -> W2b. BN is applied later in softmax.
__global__ __launch_bounds__(256) void enc_kernel(
    const float* __restrict__ W1p,
    const float* __restrict__ ew,
    float* __restrict__ W2a,
    float* __restrict__ W2b)
{
    int bid = blockIdx.x;            // ((half*4 + b)*50 + kg)*4 + h16 -> 1600 blocks
    int h16 = bid & 3;
    int t   = bid >> 2;
    int kg  = t % 50;
    int hb  = t / 50;
    int b   = hb & 3;
    int half= hb >> 2;
    int cm0 = half * 32;
    int tid = threadIdx.x;
    int w16 = tid & 15;              // w0 = w16*4
    int h   = h16 * 16 + (tid >> 4);
    int w0  = w16 * 4;
    int ko0 = kg * 2;

    // stage weights: lw[cm][g][j], cm in 0..31 (relative to cm0)
    __shared__ float lw[576];
    for (int i = tid; i < 576; i += 256) {
        int cm = i / 18, r = i - cm * 18;
        int g = r / 9, j = r - g * 9;
        lw[i] = ew[((size_t)(ko0 + g) * CMID + cm0 + cm) * 9 + j];
    }
    __syncthreads();

    const float* wb = W1p + ((size_t)b * CMID + cm0) * PPLANE;
    float acc[2][4];
#pragma unroll
    for (int g = 0; g < 2; ++g)
#pragma unroll
        for (int i = 0; i < 4; ++i) acc[g][i] = 0.f;

    bool has_l = (w16 > 0), has_r = (w16 < 15);

#pragma unroll 2
    for (int cm = 0; cm < 32; ++cm) {
        const float* p = wb + (size_t)cm * PPLANE;
        float row[3][6];             // [j][0]=w0-1, [1..4]=w0..w0+3, [5]=w0+4
#pragma unroll
        for (int j = 0; j < 3; ++j) {
            const float* rp = p + (size_t)(h + j) * Ww + w0;   // padded row h-1+j
            float4 L = *(const float4*)(rp - 4);
            float4 C = *(const float4*)(rp);
            float4 R = *(const float4*)(rp + 4);
            row[j][0] = has_l ? L.w : 0.f;
            row[j][1] = C.x; row[j][2] = C.y; row[j][3] = C.z; row[j][4] = C.w;
            row[j][5] = has_r ? R.x : 0.f;
        }

        const float* kwc = lw + cm * 18;
#pragma unroll
        for (int g = 0; g < 2; ++g) {
            const float* kw = kwc + g * 9;     // broadcast ds_read (uniform addr)
            float k0 = kw[0], k1 = kw[1], k2 = kw[2];
            float k3 = kw[3], k4 = kw[4], k5 = kw[5];
            float k6 = kw[6], k7 = kw[7], k8 = kw[8];
#pragma unroll
            for (int i = 0; i < 4; ++i)
                acc[g][i] += k0*row[0][i] + k1*row[0][i+1] + k2*row[0][i+2]
                           + k3*row[1][i] + k4*row[1][i+1] + k5*row[1][i+2]
                           + k6*row[2][i] + k7*row[2][i+1] + k8*row[2][i+2];
        }
    }

    float* dst = half ? W2b : W2a;
#pragma unroll
    for (int g = 0; g < 2; ++g) {
        float4 r = make_float4(acc[g][0], acc[g][1], acc[g][2], acc[g][3]);
        *(float4*)(dst + ((size_t)b * KOC + ko0 + g) * HW + h * Ww + w0) = r;
    }
}

// ---------------- Kernel C: combine halves + BN + softmax over 25
// Reads partials from W2a and W2b (plane layout), applies BN, softmax,
// writes result IN-PLACE into W2b's region (per-thread same addresses -> safe).
__global__ __launch_bounds__(256) void softmax_kernel(
    const float* __restrict__ W2a,
    float* __restrict__ W2b,
    const float* __restrict__ eg,
    const float* __restrict__ eb)
{
    int idx = blockIdx.x * blockDim.x + threadIdx.x;   // ((b*4+sub)*HW + pix)
    int pix = idx & (HW - 1);
    int sub = (idx >> 12) & 3;
    int b   = idx >> 14;

    float inv_s = rsqrtf(1.0f + BN_EPS);
    const float* pa = W2a + (size_t)b * KOC * HW + pix;
    float* pb       = W2b + (size_t)b * KOC * HW + pix;
    float v[25];
    float m = -1e30f;
#pragma unroll
    for (int k = 0; k < 25; ++k) {
        int ko = 4 * k + sub;                          // sub is wave-uniform
        float s  = eg[ko] * inv_s;
        float bb = eb[ko];
        v[k] = (pa[(size_t)ko * HW] + pb[(size_t)ko * HW]) * s + bb;
        m = fmaxf(m, v[k]);
    }
    float sum = 0.f;
#pragma unroll
    for (int k = 0; k < 25; ++k) {
        v[k] = expf(v[k] - m);
        sum += v[k];
    }
    float inv = 1.f / sum;
#pragma unroll
    for (int k = 0; k < 25; ++k)
        pb[(size_t)(4 * k + sub) * HW] = v[k] * inv;
}

// ---------------- Kernel D: CARAFE reassembly (weights-in-registers)
// thread = (b,h,w, chunk-of-8-channels); 100 coalesced plane loads for weights,
// then per channel: 25 shared X loads -> 4 outputs (100 FMA).
// (parity fold: floor((h2-4+2*ki)/2) = h + ki - 2 for both parities of h2)
__global__ __launch_bounds__(256) void carafe_kernel(
    const float* __restrict__ X,
    const float* __restrict__ Wsm,
    float* __restrict__ out)
{
    int gt = blockIdx.x * blockDim.x + threadIdx.x;    // (chunk*Bn + b)*HW + h*64 + w
    int w  = gt & 63;
    int h  = (gt >> 6) & 63;
    int b  = (gt >> 12) & 3;
    int chunk = gt >> 14;                              // 0..15
    int c0 = chunk * CCH;
    int pix = h * Ww + w;

    // weights from planes: wt[sub*25+k] = Wsm[b][4k+sub][pix]  (coalesced)
    float wt[100];
    const float* wpb = Wsm + (size_t)b * KOC * HW + pix;
#pragma unroll
    for (int k = 0; k < 25; ++k) {
        wt[k]      = wpb[(size_t)(4 * k + 0) * HW];
        wt[25 + k] = wpb[(size_t)(4 * k + 1) * HW];
        wt[50 + k] = wpb[(size_t)(4 * k + 2) * HW];
        wt[75 + k] = wpb[(size_t)(4 * k + 3) * HW];
    }

    int off[25];
#pragma unroll
    for (int ki = 0; ki < 5; ++ki) {
#pragma unroll
        for (int kj = 0; kj < 5; ++kj) {
            int k = ki * 5 + kj;
            int r = h + ki - 2, cc = w + kj - 2;
            bool valid = ((unsigned)r < 64u) && ((unsigned)cc < 64u);
            int rc = r < 0 ? 0 : (r > 63 ? 63 : r);
            int cx = cc < 0 ? 0 : (cc > 63 ? 63 : cc);
            off[k] = rc * Ww + cx;
            if (!valid) { wt[k] = 0.f; wt[25+k] = 0.f; wt[50+k] = 0.f; wt[75+k] = 0.f; }
        }
    }

    const float* xp = X + ((size_t)b * CIN + c0) * HW;
    float* o0 = out + ((size_t)b * CIN + c0) * HW2 + (2 * h) * W2d + 2 * w;

    for (int c = 0; c < CCH; ++c) {
        float x[25];
#pragma unroll
        for (int k = 0; k < 25; ++k) x[k] = xp[off[k]];
        float a0 = 0.f, a1 = 0.f, a2 = 0.f, a3 = 0.f;
#pragma unroll
        for (int k = 0; k < 25; ++k) {
            float xv = x[k];
            a0 += wt[k]      * xv;
            a1 += wt[25 + k] * xv;
            a2 += wt[50 + k] * xv;
            a3 += wt[75 + k] * xv;
        }
        *(float2*)o0          = make_float2(a0, a1);
        *(float2*)(o0 + W2d)  = make_float2(a2, a3);
        xp += HW;
        o0 += HW2;
    }
}

extern "C" void kernel_launch(void* const* d_in, const int* in_sizes, int n_in,
                              void* d_out, int out_size, void* d_ws, size_t ws_size,
                              hipStream_t stream)
{
    const float* X  = (const float*)d_in[0];
    const float* cw = (const float*)d_in[1];
    const float* cg = (const float*)d_in[2];
    const float* cb = (const float*)d_in[3];
    const float* ew = (const float*)d_in[4];
    const float* eg = (const float*)d_in[5];
    const float* eb = (const float*)d_in[6];
    float* out = (float*)d_out;

    float* W1p = (float*)d_ws + 64;                  // guard for rp-4 underflow
    float* W2a = W1p + (size_t)Bn * CMID * PPLANE;   // 1,081,344 floats
    float* W2b = W2a + (size_t)Bn * KOC * HW;        // 1,638,400 floats (partial half1,
                                                     //  then softmax output in-place)
    comp_kernel   <<<512, 256, 0, stream>>>(X, cw, cg, cb, W1p);
    enc_kernel    <<<2 * Bn * 50 * 4, 256, 0, stream>>>(W1p, ew, W2a, W2b);  // 1600 blocks
    softmax_kernel<<<Bn * 4 * HW / 256, 256, 0, stream>>>(W2a, W2b, eg, eb); // 256 blocks
    carafe_kernel <<<16 * Bn * HW / 256, 256, 0, stream>>>(X, W2b, out);     // 1024 blocks
}

// Round 8
// 129.181 us; speedup vs baseline: 1.2425x; 1.2425x over previous
//
#include <hip/hip_runtime.h>
#include <hip/hip_bf16.h>
#include <math.h>

#define Bn   4
#define CIN  128
#define Hh   64
#define Ww   64
#define HW   4096
#define CMID 64
#define KOC  100      // (scale*k_up)^2
#define H2   128
#define W2d  128
#define HW2  16384
#define KUP  5
#define BN_EPS 1e-5f
#define CCH  8        // channels per carafe thread (16 chunks of 8)

typedef __attribute__((ext_vector_type(4)))  short  short4v;
typedef __attribute__((ext_vector_type(8)))  short  short8v;
typedef __attribute__((ext_vector_type(16))) float  float16v;

__device__ __forceinline__ ushort f2bf(float v) {
    __hip_bfloat16 h = __float2bfloat16(v);
    return *(ushort*)&h;
}

// ---------------- Kernel A: 1x1 conv + BN + SiLU -> W1b NHWC bf16 [b][pix][64]
// Piggyback: first 288 blocks also build Abf[tap][kop 128][cm 64] bf16 (ko pad 0).
__global__ __launch_bounds__(256) void comp_kernel(
    const float* __restrict__ X,
    const float* __restrict__ cw,
    const float* __restrict__ cg,
    const float* __restrict__ cb,
    const float* __restrict__ ew,
    unsigned* __restrict__ W1b,     // [b][pix][32] packed bf16 pairs
    ushort* __restrict__ Abf)       // [9][128][64]
{
    int tid = threadIdx.x;
    if (blockIdx.x < 288) {         // A-prep: 288*256 = 73728 = 9*128*64
        int i   = blockIdx.x * 256 + tid;
        int cm  = i & 63;
        int kop = (i >> 6) & 127;
        int tap = i >> 13;
        float v = (kop < KOC) ? ew[((size_t)(kop * CMID + cm)) * 9 + tap] : 0.f;
        Abf[i] = f2bf(v);
    }

    int gt  = blockIdx.x * 256 + tid;   // 512 blocks
    int pg  = gt & 1023;
    int cog = (gt >> 10) & 31;
    int b   = gt >> 15;
    int pix = pg * 4;
    int co0 = cog * 2;

    const float* xb = X + (size_t)b * CIN * HW + pix;
    float4 acc0 = make_float4(0.f, 0.f, 0.f, 0.f);
    float4 acc1 = make_float4(0.f, 0.f, 0.f, 0.f);

#pragma unroll 4
    for (int ci = 0; ci < CIN; ++ci) {
        float4 xv = *(const float4*)(xb + (size_t)ci * HW);
        float w0 = cw[(size_t)co0 * CIN + ci];
        float w1 = cw[(size_t)(co0 + 1) * CIN + ci];
        acc0.x += xv.x * w0; acc0.y += xv.y * w0; acc0.z += xv.z * w0; acc0.w += xv.w * w0;
        acc1.x += xv.x * w1; acc1.y += xv.y * w1; acc1.z += xv.z * w1; acc1.w += xv.w * w1;
    }

    float inv_s = rsqrtf(1.0f + BN_EPS);
    float s0 = cg[co0] * inv_s,     bb0 = cb[co0];
    float s1 = cg[co0 + 1] * inv_s, bb1 = cb[co0 + 1];
    float r0[4] = {acc0.x, acc0.y, acc0.z, acc0.w};
    float r1[4] = {acc1.x, acc1.y, acc1.z, acc1.w};
#pragma unroll
    for (int i = 0; i < 4; ++i) {
        float v0 = r0[i] * s0 + bb0; v0 = v0 / (1.f + expf(-v0));
        float v1 = r1[i] * s1 + bb1; v1 = v1 / (1.f + expf(-v1));
        unsigned pk = (unsigned)f2bf(v0) | ((unsigned)f2bf(v1) << 16);
        W1b[((size_t)b * HW + pix + i) * 32 + cog] = pk;
    }
}

// ---------------- Kernel B: 3x3 conv as implicit GEMM via MFMA bf16
// C[100 pad 128][N=32 spatial] = sum_{tap,cmchunk} A x B(shifted W1 tile in LDS)
// block = (b, h, w-half); LDS tile: [3 rows][34 w][cm pad 72] bf16.
__global__ __launch_bounds__(256) void enc_kernel(
    const ushort* __restrict__ W1b_us,   // [b][pix][64] bf16
    const ushort* __restrict__ Abf,      // [9][128][64] bf16
    float* __restrict__ W2)              // [b][100][4096] fp32 (pre-BN logits)
{
    __shared__ ushort Bs[3 * 34 * 72];   // 14688 B

    int bid   = blockIdx.x;              // b*128 + h*2 + whalf -> 512 blocks
    int whalf = bid & 1;
    int h     = (bid >> 1) & 63;
    int b     = bid >> 7;
    int w0    = whalf * 32;
    int tid   = threadIdx.x;

    // stage B tile (bf16-pair granularity, coalesced in cm)
    const unsigned* src  = (const unsigned*)W1b_us;  // [b][pix][32]
    unsigned*       dstu = (unsigned*)Bs;            // w-slot stride 36 uints
    for (int i = tid; i < 3 * 34 * 32; i += 256) {
        int cp = i & 31;
        int t  = i >> 5;
        int wl = t % 34;
        int r  = t / 34;
        int gr = h - 1 + r, gw = w0 - 1 + wl;
        unsigned val = 0u;
        if ((unsigned)gr < 64u && (unsigned)gw < 64u)
            val = src[((size_t)b * HW + gr * 64 + gw) * 32 + cp];
        dstu[(r * 34 + wl) * 36 + cp] = val;
    }
    __syncthreads();

    int lane = tid & 63;
    int wid  = tid >> 6;                 // M-tile: ko base = wid*32
    int n    = lane & 31;
    int q    = lane >> 5;                // 0/1 -> k half

    float16v acc;
#pragma unroll
    for (int i = 0; i < 16; ++i) acc[i] = 0.f;

    const ushort* Arow = Abf + ((size_t)(wid * 32 + n)) * 64 + q * 8;

#pragma unroll
    for (int tap = 0; tap < 9; ++tap) {
        int dy = tap / 3, dx = tap % 3;
        int bbase = ((dy * 34) + n + dx) * 72 + q * 8;     // ushort idx, 16B aligned
        const ushort* Atap = Arow + (size_t)tap * 128 * 64;
#pragma unroll
        for (int c = 0; c < 4; ++c) {
            short8v a = *(const short8v*)(Atap + c * 16);
            short8v bf = *(const short8v*)(Bs + bbase + c * 16);
            acc = __builtin_amdgcn_mfma_f32_32x32x16_bf16(a, bf, acc, 0, 0, 0);
        }
    }

    // store: col = lane&31 = n (pixel), row = (reg&3)+8*(reg>>2)+4*q = ko offset
    int pixn = h * 64 + w0 + n;
    float* Wp = W2 + (size_t)b * KOC * HW + pixn;
#pragma unroll
    for (int reg = 0; reg < 16; ++reg) {
        int row = (reg & 3) + 8 * (reg >> 2) + 4 * q;
        int ko  = wid * 32 + row;
        if (ko < KOC) Wp[(size_t)ko * HW] = acc[reg];
    }
}

// ---------------- Kernel C: BN + pixel-shuffle softmax over 25 (plane layout)
__global__ __launch_bounds__(256) void softmax_kernel(
    const float* __restrict__ W2,
    float* __restrict__ Wsm,
    const float* __restrict__ eg,
    const float* __restrict__ eb)
{
    int idx = blockIdx.x * blockDim.x + threadIdx.x;   // ((b*4+sub)*HW + pix)
    int pix = idx & (HW - 1);
    int sub = (idx >> 12) & 3;
    int b   = idx >> 14;

    float inv_s = rsqrtf(1.0f + BN_EPS);
    const float* pi = W2  + (size_t)b * KOC * HW + pix;
    float*       po = Wsm + (size_t)b * KOC * HW + pix;
    float v[25];
    float m = -1e30f;
#pragma unroll
    for (int k = 0; k < 25; ++k) {
        int ko = 4 * k + sub;                          // wave-uniform
        v[k] = pi[(size_t)ko * HW] * (eg[ko] * inv_s) + eb[ko];
        m = fmaxf(m, v[k]);
    }
    float sum = 0.f;
#pragma unroll
    for (int k = 0; k < 25; ++k) {
        v[k] = expf(v[k] - m);
        sum += v[k];
    }
    float inv = 1.f / sum;
#pragma unroll
    for (int k = 0; k < 25; ++k)
        po[(size_t)(4 * k + sub) * HW] = v[k] * inv;
}

// ---------------- Kernel D: CARAFE reassembly (weights-in-registers)
// (parity fold: floor((h2-4+2*ki)/2) = h + ki - 2 for both parities of h2)
__global__ __launch_bounds__(256) void carafe_kernel(
    const float* __restrict__ X,
    const float* __restrict__ Wsm,
    float* __restrict__ out)
{
    int gt = blockIdx.x * blockDim.x + threadIdx.x;    // (chunk*Bn + b)*HW + h*64 + w
    int w  = gt & 63;
    int h  = (gt >> 6) & 63;
    int b  = (gt >> 12) & 3;
    int chunk = gt >> 14;                              // 0..15
    int c0 = chunk * CCH;
    int pix = h * Ww + w;

    float wt[100];
    const float* wpb = Wsm + (size_t)b * KOC * HW + pix;
#pragma unroll
    for (int k = 0; k < 25; ++k) {
        wt[k]      = wpb[(size_t)(4 * k + 0) * HW];
        wt[25 + k] = wpb[(size_t)(4 * k + 1) * HW];
        wt[50 + k] = wpb[(size_t)(4 * k + 2) * HW];
        wt[75 + k] = wpb[(size_t)(4 * k + 3) * HW];
    }

    int off[25];
#pragma unroll
    for (int ki = 0; ki < 5; ++ki) {
#pragma unroll
        for (int kj = 0; kj < 5; ++kj) {
            int k = ki * 5 + kj;
            int r = h + ki - 2, cc = w + kj - 2;
            bool valid = ((unsigned)r < 64u) && ((unsigned)cc < 64u);
            int rc = r < 0 ? 0 : (r > 63 ? 63 : r);
            int cx = cc < 0 ? 0 : (cc > 63 ? 63 : cc);
            off[k] = rc * Ww + cx;
            if (!valid) { wt[k] = 0.f; wt[25+k] = 0.f; wt[50+k] = 0.f; wt[75+k] = 0.f; }
        }
    }

    const float* xp = X + ((size_t)b * CIN + c0) * HW;
    float* o0 = out + ((size_t)b * CIN + c0) * HW2 + (2 * h) * W2d + 2 * w;

    for (int c = 0; c < CCH; ++c) {
        float x[25];
#pragma unroll
        for (int k = 0; k < 25; ++k) x[k] = xp[off[k]];
        float a0 = 0.f, a1 = 0.f, a2 = 0.f, a3 = 0.f;
#pragma unroll
        for (int k = 0; k < 25; ++k) {
            float xv = x[k];
            a0 += wt[k]      * xv;
            a1 += wt[25 + k] * xv;
            a2 += wt[50 + k] * xv;
            a3 += wt[75 + k] * xv;
        }
        *(float2*)o0          = make_float2(a0, a1);
        *(float2*)(o0 + W2d)  = make_float2(a2, a3);
        xp += HW;
        o0 += HW2;
    }
}

extern "C" void kernel_launch(void* const* d_in, const int* in_sizes, int n_in,
                              void* d_out, int out_size, void* d_ws, size_t ws_size,
                              hipStream_t stream)
{
    const float* X  = (const float*)d_in[0];
    const float* cw = (const float*)d_in[1];
    const float* cg = (const float*)d_in[2];
    const float* cb = (const float*)d_in[3];
    const float* ew = (const float*)d_in[4];
    const float* eg = (const float*)d_in[5];
    const float* eb = (const float*)d_in[6];
    float* out = (float*)d_out;

    char* ws = (char*)d_ws;
    unsigned* W1b = (unsigned*)ws;                        // 4*4096*32 u32 = 2 MB
    ushort*   Abf = (ushort*)(ws + 2097152);              // 9*128*64 = 147456 B
    float*    W2  = (float*)(ws + 2097152 + 147456);      // 6.55 MB
    float*    Wsm = W2 + (size_t)Bn * KOC * HW;           // 6.55 MB

    comp_kernel   <<<512, 256, 0, stream>>>(X, cw, cg, cb, ew, W1b, Abf);
    enc_kernel    <<<512, 256, 0, stream>>>((const ushort*)W1b, Abf, W2);
    softmax_kernel<<<Bn * 4 * HW / 256, 256, 0, stream>>>(W2, Wsm, eg, eb);
    carafe_kernel <<<16 * Bn * HW / 256, 256, 0, stream>>>(X, Wsm, out);
}